// Round 1
// baseline (837.023 us; speedup 1.0000x reference)
//
#include <hip/hip_runtime.h>

typedef _Float16 half8_t __attribute__((ext_vector_type(8)));
typedef _Float16 half4_t __attribute__((ext_vector_type(4)));
typedef float f32x4 __attribute__((ext_vector_type(4)));

#define MFMA16(a, b, c) __builtin_amdgcn_mfma_f32_16x16x32_f16((a), (b), (c), 0, 0, 0)

// ---------------- convert / transpose ----------------

__global__ void cvt_f2h_kernel(const float* __restrict__ in, _Float16* __restrict__ out, int n4) {
    int stride = gridDim.x * blockDim.x;
    for (int i = blockIdx.x * blockDim.x + threadIdx.x; i < n4; i += stride) {
        f32x4 v = *(const f32x4*)(in + (size_t)4 * i);
        half4_t h;
        h[0] = (_Float16)v[0]; h[1] = (_Float16)v[1];
        h[2] = (_Float16)v[2]; h[3] = (_Float16)v[3];
        *(half4_t*)(out + (size_t)4 * i) = h;
    }
}

// out[j][k] = in[k][j], K fixed at 768
__global__ void transpose768_kernel(const float* __restrict__ in, _Float16* __restrict__ out, int ncols) {
    int idx = blockIdx.x * 256 + threadIdx.x;
    int total = ncols * 768;
    if (idx < total) {
        int j = idx / 768;
        int k = idx - j * 768;
        out[idx] = (_Float16)in[(size_t)k * ncols + j];
    }
}

// ---------------- GEMM core: 128x128 tile, BK=64, 4 waves ----------------
// A: [M][768] f16 row-major (K contiguous); Bt: [Nout][768] f16 (K contiguous)
#define LDK 72

__device__ __forceinline__ void run_gemm(const _Float16* __restrict__ A,
                                         const _Float16* __restrict__ Bt,
                                         int mbase, int nbase,
                                         _Float16* As, _Float16* Bs,
                                         f32x4 (&acc)[4][4]) {
    const int tid = threadIdx.x;
    const int lane = tid & 63;
    const int wave = tid >> 6;
    const int wm = (wave >> 1) * 64;
    const int wn = (wave & 1) * 64;
    const int l15 = lane & 15;
    const int l4 = lane >> 4;

    #pragma unroll
    for (int mi = 0; mi < 4; ++mi)
        #pragma unroll
        for (int ni = 0; ni < 4; ++ni)
            acc[mi][ni] = (f32x4){0.f, 0.f, 0.f, 0.f};

    for (int kt = 0; kt < 12; ++kt) {
        const int kof = kt * 64;
        #pragma unroll
        for (int i = 0; i < 4; ++i) {
            int segid = tid + 256 * i;
            int row = segid >> 3, seg = segid & 7;
            half8_t av = *(const half8_t*)(A + (size_t)(mbase + row) * 768 + kof + seg * 8);
            half8_t bv = *(const half8_t*)(Bt + (size_t)(nbase + row) * 768 + kof + seg * 8);
            *(half8_t*)(As + row * LDK + seg * 8) = av;
            *(half8_t*)(Bs + row * LDK + seg * 8) = bv;
        }
        __syncthreads();
        #pragma unroll
        for (int kk = 0; kk < 64; kk += 32) {
            half8_t a[4], b[4];
            #pragma unroll
            for (int mi = 0; mi < 4; ++mi)
                a[mi] = *(const half8_t*)(As + (wm + mi * 16 + l15) * LDK + kk + l4 * 8);
            #pragma unroll
            for (int ni = 0; ni < 4; ++ni)
                b[ni] = *(const half8_t*)(Bs + (wn + ni * 16 + l15) * LDK + kk + l4 * 8);
            #pragma unroll
            for (int mi = 0; mi < 4; ++mi)
                #pragma unroll
                for (int ni = 0; ni < 4; ++ni)
                    acc[mi][ni] = MFMA16(a[mi], b[ni], acc[mi][ni]);
        }
        __syncthreads();
    }
}

// GEMM1: qkv = x @ w_qkv, epilogue: +pos_enc (k), relu (q,k), scatter to head layout
__global__ __launch_bounds__(256) void gemm_qkv_kernel(
    const _Float16* __restrict__ xh, const _Float16* __restrict__ wqkvT,
    const float* __restrict__ pos_enc,
    _Float16* __restrict__ qh, _Float16* __restrict__ kh, _Float16* __restrict__ vh) {
    __shared__ _Float16 As[128 * LDK];
    __shared__ _Float16 Bs[128 * LDK];
    int bid = blockIdx.x;
    int mtile = bid / 18, ntile = bid - mtile * 18;
    f32x4 acc[4][4];
    run_gemm(xh, wqkvT, mtile * 128, ntile * 128, As, Bs, acc);

    const int tid = threadIdx.x;
    const int lane = tid & 63;
    const int wave = tid >> 6;
    const int wm = (wave >> 1) * 64;
    const int wn = (wave & 1) * 64;
    const int l15 = lane & 15;
    const int l4 = lane >> 4;

    #pragma unroll
    for (int mi = 0; mi < 4; ++mi) {
        #pragma unroll
        for (int ni = 0; ni < 4; ++ni) {
            int gc = ntile * 128 + wn + ni * 16 + l15;
            int s = gc / 768;
            int c = gc - s * 768;
            int h = c >> 6, d = c & 63;
            _Float16* dst = (s == 0) ? qh : ((s == 1) ? kh : vh);
            #pragma unroll
            for (int r = 0; r < 4; ++r) {
                int gr = mtile * 128 + wm + mi * 16 + l4 * 4 + r;
                int b = gr / 196;
                int n = gr - b * 196;
                float v = acc[mi][ni][r];
                if (s == 1) v += pos_enc[n * 768 + c];
                if (s < 2) v = fmaxf(v, 0.f);
                dst[((size_t)(b * 12 + h) * 196 + n) * 64 + d] = (_Float16)v;
            }
        }
    }
}

// GEMM2: out = fused @ w_proj + b_proj (f32 out)
__global__ __launch_bounds__(256) void gemm_proj_kernel(
    const _Float16* __restrict__ fused, const _Float16* __restrict__ wprojT,
    const float* __restrict__ b_proj, float* __restrict__ out) {
    __shared__ _Float16 As[128 * LDK];
    __shared__ _Float16 Bs[128 * LDK];
    int bid = blockIdx.x;
    int mtile = bid / 6, ntile = bid - mtile * 6;
    f32x4 acc[4][4];
    run_gemm(fused, wprojT, mtile * 128, ntile * 128, As, Bs, acc);

    const int tid = threadIdx.x;
    const int lane = tid & 63;
    const int wave = tid >> 6;
    const int wm = (wave >> 1) * 64;
    const int wn = (wave & 1) * 64;
    const int l15 = lane & 15;
    const int l4 = lane >> 4;

    #pragma unroll
    for (int mi = 0; mi < 4; ++mi) {
        #pragma unroll
        for (int ni = 0; ni < 4; ++ni) {
            int gc = ntile * 128 + wn + ni * 16 + l15;
            float bp = b_proj[gc];
            #pragma unroll
            for (int r = 0; r < 4; ++r) {
                int gr = mtile * 128 + wm + mi * 16 + l4 * 4 + r;
                out[(size_t)gr * 768 + gc] = acc[mi][ni][r] + bp;
            }
        }
    }
}

// ---------------- attention part 1: kv = k^T v (64x64), ksum, z ----------------
// k_t/v_t: [64][232] f16 LDS, transposed (rows = channel, cols = n, zero-padded to 224+)
__global__ __launch_bounds__(512) void attn1_kernel(
    const _Float16* __restrict__ qh, const _Float16* __restrict__ kh,
    const _Float16* __restrict__ vh, _Float16* __restrict__ kvg, float* __restrict__ zg) {
    __shared__ _Float16 k_t[64 * 232];
    __shared__ _Float16 v_t[64 * 232];
    __shared__ float ksum_p[8 * 64];
    __shared__ float ksum[64];

    int bh = blockIdx.x;
    int tid = threadIdx.x;
    int lane = tid & 63, wave = tid >> 6;
    int l15 = lane & 15, l4 = lane >> 4;
    size_t base = (size_t)bh * 12544;

    // zero pad columns [196,232)
    for (int idx = tid; idx < 1152; idx += 512) {
        int c = idx / 18, u = idx - c * 18;
        ((unsigned int*)(k_t + c * 232 + 196))[u] = 0u;
        ((unsigned int*)(v_t + c * 232 + 196))[u] = 0u;
    }
    // load + transpose k, v
    for (int j = tid; j < 3136; j += 512) {
        int e = j * 4, n = e >> 6, c = e & 63;
        half4_t kq = *(const half4_t*)(kh + base + e);
        half4_t vq = *(const half4_t*)(vh + base + e);
        k_t[(c + 0) * 232 + n] = kq[0]; k_t[(c + 1) * 232 + n] = kq[1];
        k_t[(c + 2) * 232 + n] = kq[2]; k_t[(c + 3) * 232 + n] = kq[3];
        v_t[(c + 0) * 232 + n] = vq[0]; v_t[(c + 1) * 232 + n] = vq[1];
        v_t[(c + 2) * 232 + n] = vq[2]; v_t[(c + 3) * 232 + n] = vq[3];
    }
    __syncthreads();

    // kv MFMA: wave -> (ct, dt0), (ct, dt0+1)
    int ct = wave >> 1, dt0 = (wave & 1) * 2;
    f32x4 acc0 = {0.f, 0.f, 0.f, 0.f}, acc1 = {0.f, 0.f, 0.f, 0.f};
    #pragma unroll
    for (int ks = 0; ks < 7; ++ks) {
        half8_t a  = *(const half8_t*)(k_t + (ct * 16 + l15) * 232 + ks * 32 + l4 * 8);
        half8_t b0 = *(const half8_t*)(v_t + (dt0 * 16 + l15) * 232 + ks * 32 + l4 * 8);
        half8_t b1 = *(const half8_t*)(v_t + (dt0 * 16 + 16 + l15) * 232 + ks * 32 + l4 * 8);
        acc0 = MFMA16(a, b0, acc0);
        acc1 = MFMA16(a, b1, acc1);
    }
    {
        half4_t h0, h1;
        #pragma unroll
        for (int r = 0; r < 4; ++r) { h0[r] = (_Float16)acc0[r]; h1[r] = (_Float16)acc1[r]; }
        // store kv transposed: kvg[d][c]
        *(half4_t*)(kvg + (size_t)bh * 4096 + (dt0 * 16 + l15) * 64 + ct * 16 + l4 * 4) = h0;
        *(half4_t*)(kvg + (size_t)bh * 4096 + ((dt0 + 1) * 16 + l15) * 64 + ct * 16 + l4 * 4) = h1;
    }
    // ksum partials
    {
        int n0 = wave * 25;
        int n1 = (n0 + 25 < 196) ? (n0 + 25) : 196;
        float s = 0.f;
        for (int n = n0; n < n1; ++n) s += (float)k_t[lane * 232 + n];
        ksum_p[wave * 64 + lane] = s;
    }
    __syncthreads();
    if (tid < 64) {
        float s = 0.f;
        #pragma unroll
        for (int w = 0; w < 8; ++w) s += ksum_p[w * 64 + tid];
        ksum[tid] = s;
    }
    __syncthreads();
    if (tid < 196) {
        const _Float16* qrow = qh + base + tid * 64;
        float s = 0.f;
        #pragma unroll
        for (int c = 0; c < 64; ++c) s += (float)qrow[c] * ksum[c];
        zg[(size_t)bh * 196 + tid] = 1.0f / (s + 1e-6f);
    }
}

// ---------------- attention part 2: out = z*(q@kv) + dwconv(v), write fused ----------------
__global__ __launch_bounds__(512) void attn2_kernel(
    const _Float16* __restrict__ qh, const _Float16* __restrict__ vh,
    const _Float16* __restrict__ kvg, const float* __restrict__ zg,
    const float* __restrict__ dwc_w, const float* __restrict__ dwc_b,
    _Float16* __restrict__ fused) {
    __shared__ _Float16 q_l[208 * LDK];
    __shared__ _Float16 v_n[196 * 64];

    int bh = blockIdx.x;
    int bb = bh / 12, hh = bh - bb * 12;
    int tid = threadIdx.x;
    int lane = tid & 63, wave = tid >> 6;
    int l15 = lane & 15, l4 = lane >> 4;
    size_t base = (size_t)bh * 12544;

    // zero q pad rows [196,208)
    for (int i = tid; i < 432; i += 512) ((unsigned int*)(q_l + 196 * LDK))[i] = 0u;
    for (int j = tid; j < 3136; j += 512) {
        int e = j * 4, n = e >> 6, c = e & 63;
        *(half4_t*)(q_l + n * LDK + c) = *(const half4_t*)(qh + base + e);
        *(half4_t*)(v_n + e) = *(const half4_t*)(vh + base + e);
    }
    __syncthreads();

    for (int t = wave; t < 52; t += 8) {
        int mt = t >> 2, dt = t & 3;
        int d = dt * 16 + l15;
        f32x4 acc = {0.f, 0.f, 0.f, 0.f};
        half8_t a0 = *(const half8_t*)(q_l + (mt * 16 + l15) * LDK + l4 * 8);
        half8_t a1 = *(const half8_t*)(q_l + (mt * 16 + l15) * LDK + 32 + l4 * 8);
        half8_t b0 = *(const half8_t*)(kvg + (size_t)bh * 4096 + d * 64 + l4 * 8);
        half8_t b1 = *(const half8_t*)(kvg + (size_t)bh * 4096 + d * 64 + 32 + l4 * 8);
        acc = MFMA16(a0, b0, acc);
        acc = MFMA16(a1, b1, acc);

        float bd = dwc_b[d];
        float wc[25];
        #pragma unroll
        for (int j2 = 0; j2 < 25; ++j2) wc[j2] = dwc_w[d * 25 + j2];

        #pragma unroll
        for (int r = 0; r < 4; ++r) {
            int i = mt * 16 + l4 * 4 + r;
            if (i < 196) {
                int y = i / 14, x2 = i - y * 14;
                float cacc = bd;
                #pragma unroll
                for (int ky = 0; ky < 5; ++ky) {
                    int yy = y + ky - 2;
                    bool oky = (unsigned)yy < 14u;
                    #pragma unroll
                    for (int kx = 0; kx < 5; ++kx) {
                        int xx = x2 + kx - 2;
                        if (oky && (unsigned)xx < 14u)
                            cacc += (float)v_n[(yy * 14 + xx) * 64 + d] * wc[ky * 5 + kx];
                    }
                }
                float res = acc[r] * zg[(size_t)bh * 196 + i] + cacc;
                fused[((size_t)bb * 196 + i) * 768 + hh * 64 + d] = (_Float16)res;
            }
        }
    }
}

// ---------------- launcher ----------------

extern "C" void kernel_launch(void* const* d_in, const int* in_sizes, int n_in,
                              void* d_out, int out_size, void* d_ws, size_t ws_size,
                              hipStream_t stream) {
    const float* x       = (const float*)d_in[0];
    const float* w_qkv   = (const float*)d_in[1];
    const float* pos_enc = (const float*)d_in[2];
    const float* dwc_w   = (const float*)d_in[3];
    const float* dwc_b   = (const float*)d_in[4];
    const float* w_proj  = (const float*)d_in[5];
    const float* b_proj  = (const float*)d_in[6];

    const size_t NEEDED = 340574208;
    if (ws_size < NEEDED) return;  // insufficient scratch; bail (output stays poisoned)

    char* ws = (char*)d_ws;
    _Float16* xh     = (_Float16*)(ws + 0);          // 77,070,336 B (also 'fused' later)
    _Float16* fused  = xh;
    _Float16* wqkvT  = (_Float16*)(ws + 77070336);   // 3,538,944
    _Float16* wprojT = (_Float16*)(ws + 80609280);   // 1,179,648
    _Float16* qh     = (_Float16*)(ws + 81788928);   // 77,070,336
    _Float16* kh     = (_Float16*)(ws + 158859264);  // 77,070,336
    _Float16* vh     = (_Float16*)(ws + 235929600);  // 77,070,336
    _Float16* kvg    = (_Float16*)(ws + 312999936);  // 25,165,824
    float*    zg     = (float*)(ws + 338165760);     // 2,408,448

    cvt_f2h_kernel<<<4096, 256, 0, stream>>>(x, xh, 9633792);
    transpose768_kernel<<<(2304 * 768 + 255) / 256, 256, 0, stream>>>(w_qkv, wqkvT, 2304);
    transpose768_kernel<<<(768 * 768 + 255) / 256, 256, 0, stream>>>(w_proj, wprojT, 768);
    gemm_qkv_kernel<<<392 * 18, 256, 0, stream>>>(xh, wqkvT, pos_enc, qh, kh, vh);
    attn1_kernel<<<3072, 512, 0, stream>>>(qh, kh, vh, kvg, zg);
    attn2_kernel<<<3072, 512, 0, stream>>>(qh, vh, kvg, zg, dwc_w, dwc_b, fused);
    gemm_proj_kernel<<<392 * 6, 256, 0, stream>>>(fused, wprojT, b_proj, (float*)d_out);
}